// Round 5
// baseline (595.605 us; speedup 1.0000x reference)
//
#include <hip/hip_runtime.h>

#define H96 96
#define LAYERS 6
#define BN_EPS 1e-5f
#define SCAN_B 1024

typedef unsigned short u16;
typedef unsigned int u32;
typedef _Float16 f16;
typedef _Float16 h8 __attribute__((ext_vector_type(8)));
typedef float f32x4 __attribute__((ext_vector_type(4)));
typedef u32 u32x3 __attribute__((ext_vector_type(3)));

__device__ __forceinline__ float sigm(float x) { return 1.f / (1.f + __expf(-x)); }
__device__ __forceinline__ float tanh_(float x) { return 2.f / (1.f + __expf(-2.f * x)) - 1.f; }
__device__ __forceinline__ f32x4 splat4(float x) { f32x4 v = {x, x, x, x}; return v; }

struct h2s { f16 x, y; };

// unpack one dword (two f16) into two floats, by value
__device__ __forceinline__ void upk(u32 v, float& lo, float& hi) {
    union { u32 u; h2s h; } c;
    c.u = v;
    lo = (float)c.h.x;
    hi = (float)c.h.y;
}

// ---------- weight f32 -> f16 conversion ----------
__global__ void k_f2h(const float* __restrict__ convw, const float* __restrict__ wih,
                      const float* __restrict__ whh, const float* __restrict__ fc1w,
                      const float* __restrict__ fc2w, f16* __restrict__ dst) {
    int i = blockIdx.x * 256 + threadIdx.x;
    if (i >= 184320) return;
    float v;
    if (i < 55296) v = convw[i];
    else if (i < 82944) v = wih[i - 55296];
    else if (i < 110592) v = whh[i - 82944];
    else if (i < 147456) v = fc1w[i - 110592];
    else v = fc2w[i - 147456];
    dst[i] = (f16)v;
}

// ---------- WpT[l][j][k] = sum_m w_ih[j][m] * conv_w[l][k][m]  (j<288, k<96) ----------
__global__ __launch_bounds__(256) void k_wpt(const f16* __restrict__ wih16, const f16* __restrict__ convw16,
                                             f16* __restrict__ wpt) {
    int l = blockIdx.y;
    int lane = threadIdx.x & 63, wave = threadIdx.x >> 6;
    int l15 = lane & 15, q = lane >> 4;
    int rowa = blockIdx.x * 64 + wave * 16 + l15;
    if (rowa >= 288) rowa = 287;
    const f16* B = convw16 + (size_t)l * 9216;
    h8 af[3];
#pragma unroll
    for (int s = 0; s < 3; s++) af[s] = *(const h8*)(wih16 + (size_t)rowa * 96 + s * 32 + q * 8);
    f32x4 acc[6];
#pragma unroll
    for (int t = 0; t < 6; t++) acc[t] = splat4(0.f);
#pragma unroll
    for (int s = 0; s < 3; s++)
#pragma unroll
        for (int t = 0; t < 6; t++) {
            h8 b = *(const h8*)(B + (size_t)(t * 16 + l15) * 96 + s * 32 + q * 8);
            acc[t] = __builtin_amdgcn_mfma_f32_16x16x32_f16(af[s], b, acc[t], 0, 0, 0);
        }
    int rbase = blockIdx.x * 64 + wave * 16 + q * 4;
#pragma unroll
    for (int t = 0; t < 6; t++)
#pragma unroll
        for (int rr = 0; rr < 4; rr++) {
            int row = rbase + rr;
            if (row < 288) wpt[(size_t)l * 27648 + (size_t)row * 96 + t * 16 + l15] = (f16)acc[t][rr];
        }
}

// ---------- pad ----------
__global__ void k_pad(const float* __restrict__ x, f16* __restrict__ hf, int N) {
    int i = blockIdx.x * 256 + threadIdx.x;
    if (i >= N * H96) return;
    int n = i / H96, c = i - n * H96;
    float v = (c < 32) ? x[n * 32 + c] : 0.f;
    hf[i] = (f16)v;
}

// ---------- CSR build ----------
__global__ void k_hist(const int* __restrict__ key, int* __restrict__ deg, int E) {
    int e = blockIdx.x * 256 + threadIdx.x;
    if (e < E) atomicAdd(&deg[key[e]], 1);
}

__global__ __launch_bounds__(SCAN_B) void k_scan1(const int* __restrict__ deg, int* __restrict__ incl,
                                                  int* __restrict__ bsum, int N) {
    __shared__ int sh[SCAN_B];
    int i = blockIdx.x * SCAN_B + threadIdx.x;
    int v = (i < N) ? deg[i] : 0;
    sh[threadIdx.x] = v;
    __syncthreads();
    for (int off = 1; off < SCAN_B; off <<= 1) {
        int t = (threadIdx.x >= (u32)off) ? sh[threadIdx.x - off] : 0;
        __syncthreads();
        sh[threadIdx.x] += t;
        __syncthreads();
    }
    incl[blockIdx.x * SCAN_B + threadIdx.x] = sh[threadIdx.x];
    if (threadIdx.x == SCAN_B - 1) bsum[blockIdx.x] = sh[threadIdx.x];
}

__global__ void k_scan2(int* __restrict__ bsum, int nb) {
    if (blockIdx.x == 0 && threadIdx.x == 0) {
        int run = 0;
        for (int i = 0; i < nb; i++) { run += bsum[i]; bsum[i] = run; }
    }
}

__global__ void k_scan3(const int* __restrict__ deg, const int* __restrict__ incl, const int* __restrict__ bsum,
                        int* __restrict__ rs, int* __restrict__ cur, int N, int E) {
    int i = blockIdx.x * 256 + threadIdx.x;
    if (i == 0) rs[N] = E;
    if (i < N) {
        int b = i / SCAN_B;
        int off = (b > 0) ? bsum[b - 1] : 0;
        int ex = incl[i] - deg[i] + off;
        rs[i] = ex;
        if (cur) cur[i] = ex;
    }
}

__global__ void k_fill(const int* __restrict__ src, const int* __restrict__ dst, int* __restrict__ cur,
                       int* __restrict__ es, int E) {
    int e = blockIdx.x * 256 + threadIdx.x;
    if (e < E) {
        int p = atomicAdd(&cur[dst[e]], 1);
        es[p] = src[e];
    }
}

// ---------- gather: agg[n] = sum_{e in in(n)} h[src_e] ----------
// 16 nodes/block; 16-lane group per node, lane covers 6 cols (one dwordx3 per edge).
// 8-wide predicated unroll (neutral vs 4-wide; kept).
__global__ __launch_bounds__(256) void k_gather(const f16* __restrict__ hin, const int* __restrict__ rs,
                                                const int* __restrict__ es, f16* __restrict__ agg, int N) {
    int grp = threadIdx.x >> 4;
    int lane6 = threadIdx.x & 15;
    int node = blockIdx.x * 16 + grp;
    if (node >= N) return;
    int s = rs[node], e = rs[node + 1];
    float a0 = 0, a1 = 0, a2 = 0, a3 = 0, a4 = 0, a5 = 0;
    const char* basep = (const char*)hin;
    int off = lane6 * 12;
    for (int i = s; i < e; i += 8) {
        int idx[8];
        float msk[8];
        idx[0] = i; msk[0] = 1.f;
#pragma unroll
        for (int k = 1; k < 8; k++) {
            int t = i + k;
            bool v = t < e;
            idx[k] = v ? t : i;
            msk[k] = v ? 1.f : 0.f;
        }
        u32x3 vv[8];
#pragma unroll
        for (int k = 0; k < 8; k++) {
            int sn = es[idx[k]];
            vv[k] = *(const u32x3*)(basep + (size_t)sn * 192 + off);
        }
#pragma unroll
        for (int k = 0; k < 8; k++) {
            float t0, t1;
            upk(vv[k].x, t0, t1); a0 += t0 * msk[k]; a1 += t1 * msk[k];
            upk(vv[k].y, t0, t1); a2 += t0 * msk[k]; a3 += t1 * msk[k];
            upk(vv[k].z, t0, t1); a4 += t0 * msk[k]; a5 += t1 * msk[k];
        }
    }
    f16* dp = agg + (size_t)node * H96 + lane6 * 6;
    h2s p0, p1, p2;
    p0.x = (f16)a0; p0.y = (f16)a1;
    p1.x = (f16)a2; p1.y = (f16)a3;
    p2.x = (f16)a4; p2.y = (f16)a5;
    *(h2s*)(dp + 0) = p0;
    *(h2s*)(dp + 2) = p1;
    *(h2s*)(dp + 4) = p2;
}

// ---------- GRU v5: 2 row-tiles (32 rows) per wave iteration ----------
// 6 waves/block, wave w owns output cols [16w,16w+16). Round-4 diagnosis: effective
// residency is capped ~2-3 waves/SIMD by the UNIFIED VGPR+AGPR file (reported VGPR=64
// excludes AGPRs), so the grid experiment was confounded and the kernel is latency-stalled
// (~660 issue-cy vs ~3000 wall-cy per wave-tile). Lever: ILP within the wave — 12 input
// loads in flight, 8 independent MFMA chains, 2 epilogues per iteration.
__global__ __launch_bounds__(384, 2) void k_gru(const f16* __restrict__ agg, const f16* __restrict__ hin,
                                                f16* __restrict__ hout, const f16* __restrict__ wpt,
                                                const f16* __restrict__ whh, const float* __restrict__ bih,
                                                const float* __restrict__ bhh, int N) {
    int w = threadIdx.x >> 6;
    int lane = threadIdx.x & 63;
    int l15 = lane & 15, q = lane >> 4;
    int jr = w * 16 + l15;
    float b_r = bih[jr] + bhh[jr];
    float b_z = bih[96 + jr] + bhh[96 + jr];
    float b_in = bih[192 + jr];
    float b_hn = bhh[192 + jr];
    h8 wr0[3], wr1[3], wz0[3], wz1[3], wn0[3], wn1[3];
#pragma unroll
    for (int s = 0; s < 3; s++) {
        int ko = s * 32 + q * 8;
        wr0[s] = *(const h8*)(wpt + (size_t)jr * H96 + ko);
        wz0[s] = *(const h8*)(wpt + (size_t)(96 + jr) * H96 + ko);
        wn0[s] = *(const h8*)(wpt + (size_t)(192 + jr) * H96 + ko);
        wr1[s] = *(const h8*)(whh + (size_t)jr * H96 + ko);
        wz1[s] = *(const h8*)(whh + (size_t)(96 + jr) * H96 + ko);
        wn1[s] = *(const h8*)(whh + (size_t)(192 + jr) * H96 + ko);
    }
    int ntiles2 = (N + 31) >> 5;
    for (int t = blockIdx.x; t < ntiles2; t += gridDim.x) {
        int base = t << 5;
        int rowa0 = base + l15;
        int rowa1 = base + 16 + l15;
        if (rowa0 >= N) rowa0 = N - 1;
        if (rowa1 >= N) rowa1 = N - 1;
        h8 aA[3], hA[3], aB[3], hB[3];
#pragma unroll
        for (int s = 0; s < 3; s++) {
            int ko = s * 32 + q * 8;
            aA[s] = *(const h8*)(agg + (size_t)rowa0 * H96 + ko);
            hA[s] = *(const h8*)(hin + (size_t)rowa0 * H96 + ko);
            aB[s] = *(const h8*)(agg + (size_t)rowa1 * H96 + ko);
            hB[s] = *(const h8*)(hin + (size_t)rowa1 * H96 + ko);
        }
        f32x4 r0 = splat4(b_r), z0 = splat4(b_z), n0 = splat4(b_in), g0 = splat4(b_hn);
        f32x4 r1 = splat4(b_r), z1 = splat4(b_z), n1 = splat4(b_in), g1 = splat4(b_hn);
#pragma unroll
        for (int s = 0; s < 3; s++) {
            r0 = __builtin_amdgcn_mfma_f32_16x16x32_f16(aA[s], wr0[s], r0, 0, 0, 0);
            r1 = __builtin_amdgcn_mfma_f32_16x16x32_f16(aB[s], wr0[s], r1, 0, 0, 0);
            r0 = __builtin_amdgcn_mfma_f32_16x16x32_f16(hA[s], wr1[s], r0, 0, 0, 0);
            r1 = __builtin_amdgcn_mfma_f32_16x16x32_f16(hB[s], wr1[s], r1, 0, 0, 0);
            z0 = __builtin_amdgcn_mfma_f32_16x16x32_f16(aA[s], wz0[s], z0, 0, 0, 0);
            z1 = __builtin_amdgcn_mfma_f32_16x16x32_f16(aB[s], wz0[s], z1, 0, 0, 0);
            z0 = __builtin_amdgcn_mfma_f32_16x16x32_f16(hA[s], wz1[s], z0, 0, 0, 0);
            z1 = __builtin_amdgcn_mfma_f32_16x16x32_f16(hB[s], wz1[s], z1, 0, 0, 0);
            n0 = __builtin_amdgcn_mfma_f32_16x16x32_f16(aA[s], wn0[s], n0, 0, 0, 0);
            n1 = __builtin_amdgcn_mfma_f32_16x16x32_f16(aB[s], wn0[s], n1, 0, 0, 0);
            g0 = __builtin_amdgcn_mfma_f32_16x16x32_f16(hA[s], wn1[s], g0, 0, 0, 0);
            g1 = __builtin_amdgcn_mfma_f32_16x16x32_f16(hB[s], wn1[s], g1, 0, 0, 0);
        }
#pragma unroll
        for (int half = 0; half < 2; half++) {
            f32x4& r = half ? r1 : r0;
            f32x4& z = half ? z1 : z0;
            f32x4& nn = half ? n1 : n0;
            f32x4& hn = half ? g1 : g0;
            int rbase = base + half * 16 + q * 4;
#pragma unroll
            for (int rr = 0; rr < 4; rr++) {
                int row = rbase + rr;
                if (row < N) {
                    float rv = sigm(r[rr]);
                    float zv = sigm(z[rr]);
                    float nv = tanh_(nn[rr] + rv * hn[rr]);
                    size_t idx = (size_t)row * H96 + w * 16 + l15;
                    float hold = (float)hin[idx];
                    float hnew = (1.f - zv) * nv + zv * hold;
                    hout[idx] = (f16)hnew;
                }
            }
        }
    }
}

// ---------- fused pool + BN ----------
__global__ void k_pool2(const f16* __restrict__ hf, const int* __restrict__ grs,
                        const float* __restrict__ gamma, const float* __restrict__ beta,
                        f16* __restrict__ pooled, int Gn) {
    int g = blockIdx.x;
    int c = threadIdx.x;
    if (g >= Gn || c >= H96) return;
    int s = grs[g], e = grs[g + 1];
    float sum = 0.f;
    for (int n = s; n < e; n++) sum += fmaxf((float)hf[(size_t)n * H96 + c], 0.f);
    float cnt = fmaxf((float)(e - s), 1.f);
    float val = (sum / cnt) * (gamma[c] * rsqrtf(1.f + BN_EPS)) + beta[c];
    pooled[(size_t)g * H96 + c] = (f16)val;
}

// ---------- MLP GEMM: out = act(A @ W^T + b); blockIdx.y selects a column group ----------
template <int KS, int NT, int OUTW, bool RELU>
__global__ __launch_bounds__(256) void k_mlp(const f16* __restrict__ A, const f16* __restrict__ W,
                                             const float* __restrict__ bias, f16* __restrict__ out, int M) {
    int lane = threadIdx.x & 63, wave = threadIdx.x >> 6;
    int l15 = lane & 15, q = lane >> 4;
    int colBase = blockIdx.y * (NT * 16);
    int tile = blockIdx.x;
    int rowa = tile * 64 + wave * 16 + l15;
    if (rowa >= M) rowa = M - 1;
    h8 af[KS];
#pragma unroll
    for (int s = 0; s < KS; s++) af[s] = *(const h8*)(A + (size_t)rowa * (KS * 32) + s * 32 + q * 8);
    f32x4 acc[NT];
#pragma unroll
    for (int t = 0; t < NT; t++) acc[t] = splat4(0.f);
#pragma unroll
    for (int s = 0; s < KS; s++)
#pragma unroll
        for (int t = 0; t < NT; t++) {
            h8 b = *(const h8*)(W + (size_t)(colBase + t * 16 + l15) * (KS * 32) + s * 32 + q * 8);
            acc[t] = __builtin_amdgcn_mfma_f32_16x16x32_f16(af[s], b, acc[t], 0, 0, 0);
        }
    int rbase = tile * 64 + wave * 16 + q * 4;
#pragma unroll
    for (int t = 0; t < NT; t++) {
        float bv = bias[colBase + t * 16 + l15];
#pragma unroll
        for (int rr = 0; rr < 4; rr++) {
            int row = rbase + rr;
            if (row >= M) continue;
            float v = acc[t][rr] + bv;
            if (RELU) v = fmaxf(v, 0.f);
            out[(size_t)row * OUTW + colBase + t * 16 + l15] = (f16)v;
        }
    }
}

__global__ void k_mlp3(const f16* __restrict__ h2, const float* __restrict__ w, const float* __restrict__ b,
                       float* __restrict__ out, int M) {
    int g = blockIdx.x * 256 + threadIdx.x;
    if (g >= M) return;
    float acc = 0.f;
    for (int k = 0; k < H96; k++) acc += (float)h2[(size_t)g * H96 + k] * w[k];
    out[g] = acc + b[0];
}

extern "C" void kernel_launch(void* const* d_in, const int* in_sizes, int n_in, void* d_out, int out_size,
                              void* d_ws, size_t ws_size, hipStream_t stream) {
    const float* x = (const float*)d_in[0];
    const int* ei = (const int*)d_in[1];
    const int* batch = (const int*)d_in[2];
    const float* conv_w = (const float*)d_in[3];
    const float* wih = (const float*)d_in[4];
    const float* whh = (const float*)d_in[5];
    const float* bih = (const float*)d_in[6];
    const float* bhh = (const float*)d_in[7];
    const float* gamma = (const float*)d_in[8];
    const float* beta = (const float*)d_in[9];
    const float* fc1w = (const float*)d_in[10];
    const float* fc1b = (const float*)d_in[11];
    const float* fc2w = (const float*)d_in[12];
    const float* fc2b = (const float*)d_in[13];
    const float* fc3w = (const float*)d_in[14];
    const float* fc3b = (const float*)d_in[15];

    int N = in_sizes[0] / 32;
    int E = in_sizes[1] / 2;
    int Gn = out_size;  // 4096
    const int* srcp = ei;
    const int* dstp = ei + E;

    char* p = (char*)d_ws;
    auto alloc = [&](size_t bytes) -> char* {
        char* r = p;
        p += (bytes + 255) & ~(size_t)255;
        return r;
    };
    f16* hA = (f16*)alloc((size_t)N * H96 * 2);
    f16* hB = (f16*)alloc((size_t)N * H96 * 2);
    f16* aggf = (f16*)alloc((size_t)N * H96 * 2);
    f16* wf16 = (f16*)alloc((size_t)184320 * 2);
    f16* wpt = (f16*)alloc((size_t)LAYERS * 27648 * 2);
    int nb = (N + SCAN_B - 1) / SCAN_B;
    int* deg = (int*)alloc((size_t)N * 4);
    int* incl = (int*)alloc((size_t)nb * SCAN_B * 4);
    int* bsum = (int*)alloc((size_t)nb * 4);
    int* rs = (int*)alloc((size_t)(N + 1) * 4);
    int* cur = (int*)alloc((size_t)N * 4);
    int* es = (int*)alloc((size_t)E * 4);
    int nb2 = (Gn + SCAN_B - 1) / SCAN_B;
    int* gdeg = (int*)alloc((size_t)Gn * 4);
    int* gincl = (int*)alloc((size_t)nb2 * SCAN_B * 4);
    int* gbsum = (int*)alloc((size_t)nb2 * 4);
    int* grs = (int*)alloc((size_t)(Gn + 1) * 4);
    f16* pooled = (f16*)alloc((size_t)Gn * H96 * 2);
    f16* h1 = (f16*)alloc((size_t)Gn * 384 * 2);
    f16* h2 = (f16*)alloc((size_t)Gn * H96 * 2);

    f16* convw16 = wf16;
    f16* wih16 = wf16 + 55296;
    f16* whh16 = wf16 + 82944;
    f16* fc1w16 = wf16 + 110592;
    f16* fc2w16 = wf16 + 147456;

    hipMemsetAsync(deg, 0, (size_t)N * 4, stream);
    hipMemsetAsync(gdeg, 0, (size_t)Gn * 4, stream);

    k_f2h<<<720, 256, 0, stream>>>(conv_w, wih, whh, fc1w, fc2w, wf16);
    k_wpt<<<dim3(5, 6), 256, 0, stream>>>(wih16, convw16, wpt);
    k_pad<<<(N * H96 + 255) / 256, 256, 0, stream>>>(x, hA, N);
    // edge CSR (by dst)
    k_hist<<<(E + 255) / 256, 256, 0, stream>>>(dstp, deg, E);
    k_scan1<<<nb, SCAN_B, 0, stream>>>(deg, incl, bsum, N);
    k_scan2<<<1, 64, 0, stream>>>(bsum, nb);
    k_scan3<<<(N + 255) / 256, 256, 0, stream>>>(deg, incl, bsum, rs, cur, N, E);
    k_fill<<<(E + 255) / 256, 256, 0, stream>>>(srcp, dstp, cur, es, E);
    // graph CSR (batch sorted)
    k_hist<<<(N + 255) / 256, 256, 0, stream>>>(batch, gdeg, N);
    k_scan1<<<nb2, SCAN_B, 0, stream>>>(gdeg, gincl, gbsum, Gn);
    k_scan2<<<1, 64, 0, stream>>>(gbsum, nb2);
    k_scan3<<<(Gn + 255) / 256, 256, 0, stream>>>(gdeg, gincl, gbsum, grs, (int*)nullptr, Gn, N);

    int nt16 = (N + 15) / 16;
    for (int l = 0; l < LAYERS; l++) {
        f16* hin = (l & 1) ? hB : hA;
        f16* hout = (l & 1) ? hA : hB;
        k_gather<<<nt16, 256, 0, stream>>>(hin, rs, es, aggf, N);
        k_gru<<<1280, 384, 0, stream>>>(aggf, hin, hout, wpt + (size_t)l * 27648, whh16, bih, bhh, N);
    }

    k_pool2<<<Gn, 128, 0, stream>>>(hA, grs, gamma, beta, pooled, Gn);
    k_mlp<3, 6, 384, true><<<dim3((Gn + 63) / 64, 4), 256, 0, stream>>>(pooled, fc1w16, fc1b, h1, Gn);
    k_mlp<12, 6, 96, true><<<dim3((Gn + 63) / 64, 1), 256, 0, stream>>>(h1, fc2w16, fc2b, h2, Gn);
    k_mlp3<<<(Gn + 255) / 256, 256, 0, stream>>>(h2, fc3w, fc3b, (float*)d_out, Gn);
}

// Round 6
// 582.616 us; speedup vs baseline: 1.0223x; 1.0223x over previous
//
#include <hip/hip_runtime.h>

#define H96 96
#define LAYERS 6
#define BN_EPS 1e-5f
#define SCAN_B 1024

typedef unsigned short u16;
typedef unsigned int u32;
typedef _Float16 f16;
typedef _Float16 h8 __attribute__((ext_vector_type(8)));
typedef float f32x4 __attribute__((ext_vector_type(4)));
typedef u32 u32x3 __attribute__((ext_vector_type(3)));

__device__ __forceinline__ float sigm(float x) { return 1.f / (1.f + __expf(-x)); }
__device__ __forceinline__ float tanh_(float x) { return 2.f / (1.f + __expf(-2.f * x)) - 1.f; }
__device__ __forceinline__ f32x4 splat4(float x) { f32x4 v = {x, x, x, x}; return v; }

struct h2s { f16 x, y; };

// unpack one dword (two f16) into two floats, by value
__device__ __forceinline__ void upk(u32 v, float& lo, float& hi) {
    union { u32 u; h2s h; } c;
    c.u = v;
    lo = (float)c.h.x;
    hi = (float)c.h.y;
}

// ---------- weight f32 -> f16 conversion ----------
__global__ void k_f2h(const float* __restrict__ convw, const float* __restrict__ wih,
                      const float* __restrict__ whh, const float* __restrict__ fc1w,
                      const float* __restrict__ fc2w, f16* __restrict__ dst) {
    int i = blockIdx.x * 256 + threadIdx.x;
    if (i >= 184320) return;
    float v;
    if (i < 55296) v = convw[i];
    else if (i < 82944) v = wih[i - 55296];
    else if (i < 110592) v = whh[i - 82944];
    else if (i < 147456) v = fc1w[i - 110592];
    else v = fc2w[i - 147456];
    dst[i] = (f16)v;
}

// ---------- WpT[l][j][k] = sum_m w_ih[j][m] * conv_w[l][k][m]  (j<288, k<96) ----------
__global__ __launch_bounds__(256) void k_wpt(const f16* __restrict__ wih16, const f16* __restrict__ convw16,
                                             f16* __restrict__ wpt) {
    int l = blockIdx.y;
    int lane = threadIdx.x & 63, wave = threadIdx.x >> 6;
    int l15 = lane & 15, q = lane >> 4;
    int rowa = blockIdx.x * 64 + wave * 16 + l15;
    if (rowa >= 288) rowa = 287;
    const f16* B = convw16 + (size_t)l * 9216;
    h8 af[3];
#pragma unroll
    for (int s = 0; s < 3; s++) af[s] = *(const h8*)(wih16 + (size_t)rowa * 96 + s * 32 + q * 8);
    f32x4 acc[6];
#pragma unroll
    for (int t = 0; t < 6; t++) acc[t] = splat4(0.f);
#pragma unroll
    for (int s = 0; s < 3; s++)
#pragma unroll
        for (int t = 0; t < 6; t++) {
            h8 b = *(const h8*)(B + (size_t)(t * 16 + l15) * 96 + s * 32 + q * 8);
            acc[t] = __builtin_amdgcn_mfma_f32_16x16x32_f16(af[s], b, acc[t], 0, 0, 0);
        }
    int rbase = blockIdx.x * 64 + wave * 16 + q * 4;
#pragma unroll
    for (int t = 0; t < 6; t++)
#pragma unroll
        for (int rr = 0; rr < 4; rr++) {
            int row = rbase + rr;
            if (row < 288) wpt[(size_t)l * 27648 + (size_t)row * 96 + t * 16 + l15] = (f16)acc[t][rr];
        }
}

// ---------- pad ----------
__global__ void k_pad(const float* __restrict__ x, f16* __restrict__ hf, int N) {
    int i = blockIdx.x * 256 + threadIdx.x;
    if (i >= N * H96) return;
    int n = i / H96, c = i - n * H96;
    float v = (c < 32) ? x[n * 32 + c] : 0.f;
    hf[i] = (f16)v;
}

// ---------- CSR build ----------
__global__ void k_hist(const int* __restrict__ key, int* __restrict__ deg, int E) {
    int e = blockIdx.x * 256 + threadIdx.x;
    if (e < E) atomicAdd(&deg[key[e]], 1);
}

__global__ __launch_bounds__(SCAN_B) void k_scan1(const int* __restrict__ deg, int* __restrict__ incl,
                                                  int* __restrict__ bsum, int N) {
    __shared__ int sh[SCAN_B];
    int i = blockIdx.x * SCAN_B + threadIdx.x;
    int v = (i < N) ? deg[i] : 0;
    sh[threadIdx.x] = v;
    __syncthreads();
    for (int off = 1; off < SCAN_B; off <<= 1) {
        int t = (threadIdx.x >= (u32)off) ? sh[threadIdx.x - off] : 0;
        __syncthreads();
        sh[threadIdx.x] += t;
        __syncthreads();
    }
    incl[blockIdx.x * SCAN_B + threadIdx.x] = sh[threadIdx.x];
    if (threadIdx.x == SCAN_B - 1) bsum[blockIdx.x] = sh[threadIdx.x];
}

__global__ void k_scan2(int* __restrict__ bsum, int nb) {
    if (blockIdx.x == 0 && threadIdx.x == 0) {
        int run = 0;
        for (int i = 0; i < nb; i++) { run += bsum[i]; bsum[i] = run; }
    }
}

__global__ void k_scan3(const int* __restrict__ deg, const int* __restrict__ incl, const int* __restrict__ bsum,
                        int* __restrict__ rs, int* __restrict__ cur, int N, int E) {
    int i = blockIdx.x * 256 + threadIdx.x;
    if (i == 0) rs[N] = E;
    if (i < N) {
        int b = i / SCAN_B;
        int off = (b > 0) ? bsum[b - 1] : 0;
        int ex = incl[i] - deg[i] + off;
        rs[i] = ex;
        if (cur) cur[i] = ex;
    }
}

__global__ void k_fill(const int* __restrict__ src, const int* __restrict__ dst, int* __restrict__ cur,
                       int* __restrict__ es, int E) {
    int e = blockIdx.x * 256 + threadIdx.x;
    if (e < E) {
        int p = atomicAdd(&cur[dst[e]], 1);
        es[p] = src[e];
    }
}

// ---------- gather: agg[n] = sum_{e in in(n)} h[src_e] ----------
// 16 nodes/block; 16-lane group per node, lane covers 6 cols (one dwordx3 per edge).
// 8-wide predicated unroll (neutral vs 4-wide; kept).
__global__ __launch_bounds__(256) void k_gather(const f16* __restrict__ hin, const int* __restrict__ rs,
                                                const int* __restrict__ es, f16* __restrict__ agg, int N) {
    int grp = threadIdx.x >> 4;
    int lane6 = threadIdx.x & 15;
    int node = blockIdx.x * 16 + grp;
    if (node >= N) return;
    int s = rs[node], e = rs[node + 1];
    float a0 = 0, a1 = 0, a2 = 0, a3 = 0, a4 = 0, a5 = 0;
    const char* basep = (const char*)hin;
    int off = lane6 * 12;
    for (int i = s; i < e; i += 8) {
        int idx[8];
        float msk[8];
        idx[0] = i; msk[0] = 1.f;
#pragma unroll
        for (int k = 1; k < 8; k++) {
            int t = i + k;
            bool v = t < e;
            idx[k] = v ? t : i;
            msk[k] = v ? 1.f : 0.f;
        }
        u32x3 vv[8];
#pragma unroll
        for (int k = 0; k < 8; k++) {
            int sn = es[idx[k]];
            vv[k] = *(const u32x3*)(basep + (size_t)sn * 192 + off);
        }
#pragma unroll
        for (int k = 0; k < 8; k++) {
            float t0, t1;
            upk(vv[k].x, t0, t1); a0 += t0 * msk[k]; a1 += t1 * msk[k];
            upk(vv[k].y, t0, t1); a2 += t0 * msk[k]; a3 += t1 * msk[k];
            upk(vv[k].z, t0, t1); a4 += t0 * msk[k]; a5 += t1 * msk[k];
        }
    }
    f16* dp = agg + (size_t)node * H96 + lane6 * 6;
    h2s p0, p1, p2;
    p0.x = (f16)a0; p0.y = (f16)a1;
    p1.x = (f16)a2; p1.y = (f16)a3;
    p2.x = (f16)a4; p2.y = (f16)a5;
    *(h2s*)(dp + 0) = p0;
    *(h2s*)(dp + 2) = p1;
    *(h2s*)(dp + 4) = p2;
}

// ---------- GRU v6: 12-wave blocks (two independent 16-row tiles per block) ----------
// Waves 0-5 process tile 2t (cols 16w..16w+16), waves 6-11 process tile 2t+1. No barrier,
// no shared state — identical per-wave code to the proven r0 kernel. Hypothesis being
// tested: occupancy ~21% == exactly ONE 6-wave block resident per CU (6/32=18.75%), i.e.
// residency is block-granularity-limited, so a 12-wave block doubles resident waves.
// All prior levers (grid size, weight pinning, LDS staging, ILP) were occupancy-invariant.
__global__ __launch_bounds__(768, 3) void k_gru(const f16* __restrict__ agg, const f16* __restrict__ hin,
                                                f16* __restrict__ hout, const f16* __restrict__ wpt,
                                                const f16* __restrict__ whh, const float* __restrict__ bih,
                                                const float* __restrict__ bhh, int N) {
    int w2 = threadIdx.x >> 6;          // 0..11
    int half = (w2 >= 6) ? 1 : 0;       // which tile of the pair
    int w = w2 - half * 6;              // 0..5: column-tile owner
    int lane = threadIdx.x & 63;
    int l15 = lane & 15, q = lane >> 4;
    int jr = w * 16 + l15;
    float b_r = bih[jr] + bhh[jr];
    float b_z = bih[96 + jr] + bhh[96 + jr];
    float b_in = bih[192 + jr];
    float b_hn = bhh[192 + jr];
    h8 wr0[3], wr1[3], wz0[3], wz1[3], wn0[3], wn1[3];
#pragma unroll
    for (int s = 0; s < 3; s++) {
        int ko = s * 32 + q * 8;
        wr0[s] = *(const h8*)(wpt + (size_t)jr * H96 + ko);
        wz0[s] = *(const h8*)(wpt + (size_t)(96 + jr) * H96 + ko);
        wn0[s] = *(const h8*)(wpt + (size_t)(192 + jr) * H96 + ko);
        wr1[s] = *(const h8*)(whh + (size_t)jr * H96 + ko);
        wz1[s] = *(const h8*)(whh + (size_t)(96 + jr) * H96 + ko);
        wn1[s] = *(const h8*)(whh + (size_t)(192 + jr) * H96 + ko);
    }
    int npairs = (N + 31) >> 5;
    for (int t = blockIdx.x; t < npairs; t += gridDim.x) {
        int tile = t * 2 + half;
        int base = tile << 4;
        if (base >= N) continue;
        int rowa = base + l15;
        if (rowa >= N) rowa = N - 1;
        h8 as_[3], ah[3];
#pragma unroll
        for (int s = 0; s < 3; s++) {
            as_[s] = *(const h8*)(agg + (size_t)rowa * H96 + s * 32 + q * 8);
            ah[s] = *(const h8*)(hin + (size_t)rowa * H96 + s * 32 + q * 8);
        }
        f32x4 r = splat4(b_r), z = splat4(b_z), nn = splat4(b_in), hn = splat4(b_hn);
#pragma unroll
        for (int s = 0; s < 3; s++) {
            r = __builtin_amdgcn_mfma_f32_16x16x32_f16(as_[s], wr0[s], r, 0, 0, 0);
            r = __builtin_amdgcn_mfma_f32_16x16x32_f16(ah[s], wr1[s], r, 0, 0, 0);
            z = __builtin_amdgcn_mfma_f32_16x16x32_f16(as_[s], wz0[s], z, 0, 0, 0);
            z = __builtin_amdgcn_mfma_f32_16x16x32_f16(ah[s], wz1[s], z, 0, 0, 0);
            nn = __builtin_amdgcn_mfma_f32_16x16x32_f16(as_[s], wn0[s], nn, 0, 0, 0);
            hn = __builtin_amdgcn_mfma_f32_16x16x32_f16(ah[s], wn1[s], hn, 0, 0, 0);
        }
        int rbase = base + q * 4;
#pragma unroll
        for (int rr = 0; rr < 4; rr++) {
            int row = rbase + rr;
            if (row < N) {
                float rv = sigm(r[rr]);
                float zv = sigm(z[rr]);
                float nv = tanh_(nn[rr] + rv * hn[rr]);
                size_t idx = (size_t)row * H96 + w * 16 + l15;
                float hold = (float)hin[idx];
                float hnew = (1.f - zv) * nv + zv * hold;
                hout[idx] = (f16)hnew;
            }
        }
    }
}

// ---------- fused pool + BN ----------
__global__ void k_pool2(const f16* __restrict__ hf, const int* __restrict__ grs,
                        const float* __restrict__ gamma, const float* __restrict__ beta,
                        f16* __restrict__ pooled, int Gn) {
    int g = blockIdx.x;
    int c = threadIdx.x;
    if (g >= Gn || c >= H96) return;
    int s = grs[g], e = grs[g + 1];
    float sum = 0.f;
    for (int n = s; n < e; n++) sum += fmaxf((float)hf[(size_t)n * H96 + c], 0.f);
    float cnt = fmaxf((float)(e - s), 1.f);
    float val = (sum / cnt) * (gamma[c] * rsqrtf(1.f + BN_EPS)) + beta[c];
    pooled[(size_t)g * H96 + c] = (f16)val;
}

// ---------- MLP GEMM: out = act(A @ W^T + b); blockIdx.y selects a column group ----------
template <int KS, int NT, int OUTW, bool RELU>
__global__ __launch_bounds__(256) void k_mlp(const f16* __restrict__ A, const f16* __restrict__ W,
                                             const float* __restrict__ bias, f16* __restrict__ out, int M) {
    int lane = threadIdx.x & 63, wave = threadIdx.x >> 6;
    int l15 = lane & 15, q = lane >> 4;
    int colBase = blockIdx.y * (NT * 16);
    int tile = blockIdx.x;
    int rowa = tile * 64 + wave * 16 + l15;
    if (rowa >= M) rowa = M - 1;
    h8 af[KS];
#pragma unroll
    for (int s = 0; s < KS; s++) af[s] = *(const h8*)(A + (size_t)rowa * (KS * 32) + s * 32 + q * 8);
    f32x4 acc[NT];
#pragma unroll
    for (int t = 0; t < NT; t++) acc[t] = splat4(0.f);
#pragma unroll
    for (int s = 0; s < KS; s++)
#pragma unroll
        for (int t = 0; t < NT; t++) {
            h8 b = *(const h8*)(W + (size_t)(colBase + t * 16 + l15) * (KS * 32) + s * 32 + q * 8);
            acc[t] = __builtin_amdgcn_mfma_f32_16x16x32_f16(af[s], b, acc[t], 0, 0, 0);
        }
    int rbase = tile * 64 + wave * 16 + q * 4;
#pragma unroll
    for (int t = 0; t < NT; t++) {
        float bv = bias[colBase + t * 16 + l15];
#pragma unroll
        for (int rr = 0; rr < 4; rr++) {
            int row = rbase + rr;
            if (row >= M) continue;
            float v = acc[t][rr] + bv;
            if (RELU) v = fmaxf(v, 0.f);
            out[(size_t)row * OUTW + colBase + t * 16 + l15] = (f16)v;
        }
    }
}

__global__ void k_mlp3(const f16* __restrict__ h2, const float* __restrict__ w, const float* __restrict__ b,
                       float* __restrict__ out, int M) {
    int g = blockIdx.x * 256 + threadIdx.x;
    if (g >= M) return;
    float acc = 0.f;
    for (int k = 0; k < H96; k++) acc += (float)h2[(size_t)g * H96 + k] * w[k];
    out[g] = acc + b[0];
}

extern "C" void kernel_launch(void* const* d_in, const int* in_sizes, int n_in, void* d_out, int out_size,
                              void* d_ws, size_t ws_size, hipStream_t stream) {
    const float* x = (const float*)d_in[0];
    const int* ei = (const int*)d_in[1];
    const int* batch = (const int*)d_in[2];
    const float* conv_w = (const float*)d_in[3];
    const float* wih = (const float*)d_in[4];
    const float* whh = (const float*)d_in[5];
    const float* bih = (const float*)d_in[6];
    const float* bhh = (const float*)d_in[7];
    const float* gamma = (const float*)d_in[8];
    const float* beta = (const float*)d_in[9];
    const float* fc1w = (const float*)d_in[10];
    const float* fc1b = (const float*)d_in[11];
    const float* fc2w = (const float*)d_in[12];
    const float* fc2b = (const float*)d_in[13];
    const float* fc3w = (const float*)d_in[14];
    const float* fc3b = (const float*)d_in[15];

    int N = in_sizes[0] / 32;
    int E = in_sizes[1] / 2;
    int Gn = out_size;  // 4096
    const int* srcp = ei;
    const int* dstp = ei + E;

    char* p = (char*)d_ws;
    auto alloc = [&](size_t bytes) -> char* {
        char* r = p;
        p += (bytes + 255) & ~(size_t)255;
        return r;
    };
    f16* hA = (f16*)alloc((size_t)N * H96 * 2);
    f16* hB = (f16*)alloc((size_t)N * H96 * 2);
    f16* aggf = (f16*)alloc((size_t)N * H96 * 2);
    f16* wf16 = (f16*)alloc((size_t)184320 * 2);
    f16* wpt = (f16*)alloc((size_t)LAYERS * 27648 * 2);
    int nb = (N + SCAN_B - 1) / SCAN_B;
    int* deg = (int*)alloc((size_t)N * 4);
    int* incl = (int*)alloc((size_t)nb * SCAN_B * 4);
    int* bsum = (int*)alloc((size_t)nb * 4);
    int* rs = (int*)alloc((size_t)(N + 1) * 4);
    int* cur = (int*)alloc((size_t)N * 4);
    int* es = (int*)alloc((size_t)E * 4);
    int nb2 = (Gn + SCAN_B - 1) / SCAN_B;
    int* gdeg = (int*)alloc((size_t)Gn * 4);
    int* gincl = (int*)alloc((size_t)nb2 * SCAN_B * 4);
    int* gbsum = (int*)alloc((size_t)nb2 * 4);
    int* grs = (int*)alloc((size_t)(Gn + 1) * 4);
    f16* pooled = (f16*)alloc((size_t)Gn * H96 * 2);
    f16* h1 = (f16*)alloc((size_t)Gn * 384 * 2);
    f16* h2 = (f16*)alloc((size_t)Gn * H96 * 2);

    f16* convw16 = wf16;
    f16* wih16 = wf16 + 55296;
    f16* whh16 = wf16 + 82944;
    f16* fc1w16 = wf16 + 110592;
    f16* fc2w16 = wf16 + 147456;

    hipMemsetAsync(deg, 0, (size_t)N * 4, stream);
    hipMemsetAsync(gdeg, 0, (size_t)Gn * 4, stream);

    k_f2h<<<720, 256, 0, stream>>>(conv_w, wih, whh, fc1w, fc2w, wf16);
    k_wpt<<<dim3(5, 6), 256, 0, stream>>>(wih16, convw16, wpt);
    k_pad<<<(N * H96 + 255) / 256, 256, 0, stream>>>(x, hA, N);
    // edge CSR (by dst)
    k_hist<<<(E + 255) / 256, 256, 0, stream>>>(dstp, deg, E);
    k_scan1<<<nb, SCAN_B, 0, stream>>>(deg, incl, bsum, N);
    k_scan2<<<1, 64, 0, stream>>>(bsum, nb);
    k_scan3<<<(N + 255) / 256, 256, 0, stream>>>(deg, incl, bsum, rs, cur, N, E);
    k_fill<<<(E + 255) / 256, 256, 0, stream>>>(srcp, dstp, cur, es, E);
    // graph CSR (batch sorted)
    k_hist<<<(N + 255) / 256, 256, 0, stream>>>(batch, gdeg, N);
    k_scan1<<<nb2, SCAN_B, 0, stream>>>(gdeg, gincl, gbsum, Gn);
    k_scan2<<<1, 64, 0, stream>>>(gbsum, nb2);
    k_scan3<<<(Gn + 255) / 256, 256, 0, stream>>>(gdeg, gincl, gbsum, grs, (int*)nullptr, Gn, N);

    int nt16 = (N + 15) / 16;
    for (int l = 0; l < LAYERS; l++) {
        f16* hin = (l & 1) ? hB : hA;
        f16* hout = (l & 1) ? hA : hB;
        k_gather<<<nt16, 256, 0, stream>>>(hin, rs, es, aggf, N);
        k_gru<<<640, 768, 0, stream>>>(aggf, hin, hout, wpt + (size_t)l * 27648, whh16, bih, bhh, N);
    }

    k_pool2<<<Gn, 128, 0, stream>>>(hA, grs, gamma, beta, pooled, Gn);
    k_mlp<3, 6, 384, true><<<dim3((Gn + 63) / 64, 4), 256, 0, stream>>>(pooled, fc1w16, fc1b, h1, Gn);
    k_mlp<12, 6, 96, true><<<dim3((Gn + 63) / 64, 1), 256, 0, stream>>>(h1, fc2w16, fc2b, h2, Gn);
    k_mlp3<<<(Gn + 255) / 256, 256, 0, stream>>>(h2, fc3w, fc3b, (float*)d_out, Gn);
}

// Round 7
// 573.803 us; speedup vs baseline: 1.0380x; 1.0154x over previous
//
#include <hip/hip_runtime.h>

#define H96 96
#define LAYERS 6
#define BN_EPS 1e-5f
#define SCAN_B 1024

typedef unsigned short u16;
typedef unsigned int u32;
typedef _Float16 f16;
typedef _Float16 h8 __attribute__((ext_vector_type(8)));
typedef float f32x4 __attribute__((ext_vector_type(4)));
typedef u32 u32x3 __attribute__((ext_vector_type(3)));

__device__ __forceinline__ float sigm(float x) { return 1.f / (1.f + __expf(-x)); }
__device__ __forceinline__ float tanh_(float x) { return 2.f / (1.f + __expf(-2.f * x)) - 1.f; }
__device__ __forceinline__ f32x4 splat4(float x) { f32x4 v = {x, x, x, x}; return v; }

struct h2s { f16 x, y; };

// unpack one dword (two f16) into two floats, by value
__device__ __forceinline__ void upk(u32 v, float& lo, float& hi) {
    union { u32 u; h2s h; } c;
    c.u = v;
    lo = (float)c.h.x;
    hi = (float)c.h.y;
}

// ---------- weight f32 -> f16 conversion ----------
__global__ void k_f2h(const float* __restrict__ convw, const float* __restrict__ wih,
                      const float* __restrict__ whh, const float* __restrict__ fc1w,
                      const float* __restrict__ fc2w, f16* __restrict__ dst) {
    int i = blockIdx.x * 256 + threadIdx.x;
    if (i >= 184320) return;
    float v;
    if (i < 55296) v = convw[i];
    else if (i < 82944) v = wih[i - 55296];
    else if (i < 110592) v = whh[i - 82944];
    else if (i < 147456) v = fc1w[i - 110592];
    else v = fc2w[i - 147456];
    dst[i] = (f16)v;
}

// ---------- WpT[l][j][k] = sum_m w_ih[j][m] * conv_w[l][k][m]  (j<288, k<96) ----------
__global__ __launch_bounds__(256) void k_wpt(const f16* __restrict__ wih16, const f16* __restrict__ convw16,
                                             f16* __restrict__ wpt) {
    int l = blockIdx.y;
    int lane = threadIdx.x & 63, wave = threadIdx.x >> 6;
    int l15 = lane & 15, q = lane >> 4;
    int rowa = blockIdx.x * 64 + wave * 16 + l15;
    if (rowa >= 288) rowa = 287;
    const f16* B = convw16 + (size_t)l * 9216;
    h8 af[3];
#pragma unroll
    for (int s = 0; s < 3; s++) af[s] = *(const h8*)(wih16 + (size_t)rowa * 96 + s * 32 + q * 8);
    f32x4 acc[6];
#pragma unroll
    for (int t = 0; t < 6; t++) acc[t] = splat4(0.f);
#pragma unroll
    for (int s = 0; s < 3; s++)
#pragma unroll
        for (int t = 0; t < 6; t++) {
            h8 b = *(const h8*)(B + (size_t)(t * 16 + l15) * 96 + s * 32 + q * 8);
            acc[t] = __builtin_amdgcn_mfma_f32_16x16x32_f16(af[s], b, acc[t], 0, 0, 0);
        }
    int rbase = blockIdx.x * 64 + wave * 16 + q * 4;
#pragma unroll
    for (int t = 0; t < 6; t++)
#pragma unroll
        for (int rr = 0; rr < 4; rr++) {
            int row = rbase + rr;
            if (row < 288) wpt[(size_t)l * 27648 + (size_t)row * 96 + t * 16 + l15] = (f16)acc[t][rr];
        }
}

// ---------- pad ----------
__global__ void k_pad(const float* __restrict__ x, f16* __restrict__ hf, int N) {
    int i = blockIdx.x * 256 + threadIdx.x;
    if (i >= N * H96) return;
    int n = i / H96, c = i - n * H96;
    float v = (c < 32) ? x[n * 32 + c] : 0.f;
    hf[i] = (f16)v;
}

// ---------- CSR build ----------
__global__ void k_hist(const int* __restrict__ key, int* __restrict__ deg, int E) {
    int e = blockIdx.x * 256 + threadIdx.x;
    if (e < E) atomicAdd(&deg[key[e]], 1);
}

__global__ __launch_bounds__(SCAN_B) void k_scan1(const int* __restrict__ deg, int* __restrict__ incl,
                                                  int* __restrict__ bsum, int N) {
    __shared__ int sh[SCAN_B];
    int i = blockIdx.x * SCAN_B + threadIdx.x;
    int v = (i < N) ? deg[i] : 0;
    sh[threadIdx.x] = v;
    __syncthreads();
    for (int off = 1; off < SCAN_B; off <<= 1) {
        int t = (threadIdx.x >= (u32)off) ? sh[threadIdx.x - off] : 0;
        __syncthreads();
        sh[threadIdx.x] += t;
        __syncthreads();
    }
    incl[blockIdx.x * SCAN_B + threadIdx.x] = sh[threadIdx.x];
    if (threadIdx.x == SCAN_B - 1) bsum[blockIdx.x] = sh[threadIdx.x];
}

__global__ void k_scan2(int* __restrict__ bsum, int nb) {
    if (blockIdx.x == 0 && threadIdx.x == 0) {
        int run = 0;
        for (int i = 0; i < nb; i++) { run += bsum[i]; bsum[i] = run; }
    }
}

__global__ void k_scan3(const int* __restrict__ deg, const int* __restrict__ incl, const int* __restrict__ bsum,
                        int* __restrict__ rs, int* __restrict__ cur, int N, int E) {
    int i = blockIdx.x * 256 + threadIdx.x;
    if (i == 0) rs[N] = E;
    if (i < N) {
        int b = i / SCAN_B;
        int off = (b > 0) ? bsum[b - 1] : 0;
        int ex = incl[i] - deg[i] + off;
        rs[i] = ex;
        if (cur) cur[i] = ex;
    }
}

__global__ void k_fill(const int* __restrict__ src, const int* __restrict__ dst, int* __restrict__ cur,
                       int* __restrict__ es, int E) {
    int e = blockIdx.x * 256 + threadIdx.x;
    if (e < E) {
        int p = atomicAdd(&cur[dst[e]], 1);
        es[p] = src[e];
    }
}

// ---------- gather: agg[n] = sum_{e in in(n)} h[src_e] ----------
// 16 nodes/block-tile; 16-lane group per node, lane covers 6 cols (one dwordx3 per edge).
// 8-wide predicated unroll; v7: persistent grid-stride (1280 blocks) to amortize launches.
__global__ __launch_bounds__(256) void k_gather(const f16* __restrict__ hin, const int* __restrict__ rs,
                                                const int* __restrict__ es, f16* __restrict__ agg, int N) {
    int grp = threadIdx.x >> 4;
    int lane6 = threadIdx.x & 15;
    const char* basep = (const char*)hin;
    int off = lane6 * 12;
    int ntiles = (N + 15) >> 4;
    for (int tile = blockIdx.x; tile < ntiles; tile += gridDim.x) {
        int node = tile * 16 + grp;
        if (node >= N) continue;
        int s = rs[node], e = rs[node + 1];
        float a0 = 0, a1 = 0, a2 = 0, a3 = 0, a4 = 0, a5 = 0;
        for (int i = s; i < e; i += 8) {
            int idx[8];
            float msk[8];
            idx[0] = i; msk[0] = 1.f;
#pragma unroll
            for (int k = 1; k < 8; k++) {
                int t = i + k;
                bool v = t < e;
                idx[k] = v ? t : i;
                msk[k] = v ? 1.f : 0.f;
            }
            u32x3 vv[8];
#pragma unroll
            for (int k = 0; k < 8; k++) {
                int sn = es[idx[k]];
                vv[k] = *(const u32x3*)(basep + (size_t)sn * 192 + off);
            }
#pragma unroll
            for (int k = 0; k < 8; k++) {
                float t0, t1;
                upk(vv[k].x, t0, t1); a0 += t0 * msk[k]; a1 += t1 * msk[k];
                upk(vv[k].y, t0, t1); a2 += t0 * msk[k]; a3 += t1 * msk[k];
                upk(vv[k].z, t0, t1); a4 += t0 * msk[k]; a5 += t1 * msk[k];
            }
        }
        f16* dp = agg + (size_t)node * H96 + lane6 * 6;
        h2s p0, p1, p2;
        p0.x = (f16)a0; p0.y = (f16)a1;
        p1.x = (f16)a2; p1.y = (f16)a3;
        p2.x = (f16)a4; p2.y = (f16)a5;
        *(h2s*)(dp + 0) = p0;
        *(h2s*)(dp + 2) = p1;
        *(h2s*)(dp + 4) = p2;
    }
}

// ---------- GRU v7: r0 structure + HOISTED hold loads ----------
// 6 waves/block, wave w owns output cols [16w,16w+16); grid-stride over 16-row tiles.
// Surviving theory after 7 refutations: the per-tile serial chain was
//   frag-load wait (~900cy, cross-kernel L2 flush) -> MFMA -> hold loads issued in the
//   EPILOGUE (+~900cy exposed) -> VALU tail.
// Fix: issue the 4 hold loads together with the 6 fragment loads at loop top so the chain
// pays ONE memory wait, not two. Everything else identical to the proven r0/r4 kernel.
__global__ __launch_bounds__(384, 4) void k_gru(const f16* __restrict__ agg, const f16* __restrict__ hin,
                                                f16* __restrict__ hout, const f16* __restrict__ wpt,
                                                const f16* __restrict__ whh, const float* __restrict__ bih,
                                                const float* __restrict__ bhh, int N) {
    int w = threadIdx.x >> 6;
    int lane = threadIdx.x & 63;
    int l15 = lane & 15, q = lane >> 4;
    int jr = w * 16 + l15;
    float b_r = bih[jr] + bhh[jr];
    float b_z = bih[96 + jr] + bhh[96 + jr];
    float b_in = bih[192 + jr];
    float b_hn = bhh[192 + jr];
    h8 wr0[3], wr1[3], wz0[3], wz1[3], wn0[3], wn1[3];
#pragma unroll
    for (int s = 0; s < 3; s++) {
        int ko = s * 32 + q * 8;
        wr0[s] = *(const h8*)(wpt + (size_t)jr * H96 + ko);
        wz0[s] = *(const h8*)(wpt + (size_t)(96 + jr) * H96 + ko);
        wn0[s] = *(const h8*)(wpt + (size_t)(192 + jr) * H96 + ko);
        wr1[s] = *(const h8*)(whh + (size_t)jr * H96 + ko);
        wz1[s] = *(const h8*)(whh + (size_t)(96 + jr) * H96 + ko);
        wn1[s] = *(const h8*)(whh + (size_t)(192 + jr) * H96 + ko);
    }
    int ntiles = (N + 15) >> 4;
    for (int tile = blockIdx.x; tile < ntiles; tile += gridDim.x) {
        int base = tile << 4;
        int rowa = base + l15;
        if (rowa >= N) rowa = N - 1;
        int rbase = base + q * 4;
        // issue ALL memory for this tile up front: 6 fragment loads + 4 hold loads
        h8 as_[3], ah[3];
#pragma unroll
        for (int s = 0; s < 3; s++) {
            as_[s] = *(const h8*)(agg + (size_t)rowa * H96 + s * 32 + q * 8);
            ah[s] = *(const h8*)(hin + (size_t)rowa * H96 + s * 32 + q * 8);
        }
        float hv[4];
#pragma unroll
        for (int rr = 0; rr < 4; rr++) {
            int rw = rbase + rr;
            if (rw >= N) rw = N - 1;
            hv[rr] = (float)hin[(size_t)rw * H96 + w * 16 + l15];
        }
        f32x4 r = splat4(b_r), z = splat4(b_z), nn = splat4(b_in), hn = splat4(b_hn);
#pragma unroll
        for (int s = 0; s < 3; s++) {
            r = __builtin_amdgcn_mfma_f32_16x16x32_f16(as_[s], wr0[s], r, 0, 0, 0);
            r = __builtin_amdgcn_mfma_f32_16x16x32_f16(ah[s], wr1[s], r, 0, 0, 0);
            z = __builtin_amdgcn_mfma_f32_16x16x32_f16(as_[s], wz0[s], z, 0, 0, 0);
            z = __builtin_amdgcn_mfma_f32_16x16x32_f16(ah[s], wz1[s], z, 0, 0, 0);
            nn = __builtin_amdgcn_mfma_f32_16x16x32_f16(as_[s], wn0[s], nn, 0, 0, 0);
            hn = __builtin_amdgcn_mfma_f32_16x16x32_f16(ah[s], wn1[s], hn, 0, 0, 0);
        }
#pragma unroll
        for (int rr = 0; rr < 4; rr++) {
            int row = rbase + rr;
            if (row < N) {
                float rv = sigm(r[rr]);
                float zv = sigm(z[rr]);
                float nv = tanh_(nn[rr] + rv * hn[rr]);
                float hnew = (1.f - zv) * nv + zv * hv[rr];
                hout[(size_t)row * H96 + w * 16 + l15] = (f16)hnew;
            }
        }
    }
}

// ---------- fused pool + BN ----------
__global__ void k_pool2(const f16* __restrict__ hf, const int* __restrict__ grs,
                        const float* __restrict__ gamma, const float* __restrict__ beta,
                        f16* __restrict__ pooled, int Gn) {
    int g = blockIdx.x;
    int c = threadIdx.x;
    if (g >= Gn || c >= H96) return;
    int s = grs[g], e = grs[g + 1];
    float sum = 0.f;
    for (int n = s; n < e; n++) sum += fmaxf((float)hf[(size_t)n * H96 + c], 0.f);
    float cnt = fmaxf((float)(e - s), 1.f);
    float val = (sum / cnt) * (gamma[c] * rsqrtf(1.f + BN_EPS)) + beta[c];
    pooled[(size_t)g * H96 + c] = (f16)val;
}

// ---------- MLP GEMM: out = act(A @ W^T + b); blockIdx.y selects a column group ----------
template <int KS, int NT, int OUTW, bool RELU>
__global__ __launch_bounds__(256) void k_mlp(const f16* __restrict__ A, const f16* __restrict__ W,
                                             const float* __restrict__ bias, f16* __restrict__ out, int M) {
    int lane = threadIdx.x & 63, wave = threadIdx.x >> 6;
    int l15 = lane & 15, q = lane >> 4;
    int colBase = blockIdx.y * (NT * 16);
    int tile = blockIdx.x;
    int rowa = tile * 64 + wave * 16 + l15;
    if (rowa >= M) rowa = M - 1;
    h8 af[KS];
#pragma unroll
    for (int s = 0; s < KS; s++) af[s] = *(const h8*)(A + (size_t)rowa * (KS * 32) + s * 32 + q * 8);
    f32x4 acc[NT];
#pragma unroll
    for (int t = 0; t < NT; t++) acc[t] = splat4(0.f);
#pragma unroll
    for (int s = 0; s < KS; s++)
#pragma unroll
        for (int t = 0; t < NT; t++) {
            h8 b = *(const h8*)(W + (size_t)(colBase + t * 16 + l15) * (KS * 32) + s * 32 + q * 8);
            acc[t] = __builtin_amdgcn_mfma_f32_16x16x32_f16(af[s], b, acc[t], 0, 0, 0);
        }
    int rbase = tile * 64 + wave * 16 + q * 4;
#pragma unroll
    for (int t = 0; t < NT; t++) {
        float bv = bias[colBase + t * 16 + l15];
#pragma unroll
        for (int rr = 0; rr < 4; rr++) {
            int row = rbase + rr;
            if (row >= M) continue;
            float v = acc[t][rr] + bv;
            if (RELU) v = fmaxf(v, 0.f);
            out[(size_t)row * OUTW + colBase + t * 16 + l15] = (f16)v;
        }
    }
}

__global__ void k_mlp3(const f16* __restrict__ h2, const float* __restrict__ w, const float* __restrict__ b,
                       float* __restrict__ out, int M) {
    int g = blockIdx.x * 256 + threadIdx.x;
    if (g >= M) return;
    float acc = 0.f;
    for (int k = 0; k < H96; k++) acc += (float)h2[(size_t)g * H96 + k] * w[k];
    out[g] = acc + b[0];
}

extern "C" void kernel_launch(void* const* d_in, const int* in_sizes, int n_in, void* d_out, int out_size,
                              void* d_ws, size_t ws_size, hipStream_t stream) {
    const float* x = (const float*)d_in[0];
    const int* ei = (const int*)d_in[1];
    const int* batch = (const int*)d_in[2];
    const float* conv_w = (const float*)d_in[3];
    const float* wih = (const float*)d_in[4];
    const float* whh = (const float*)d_in[5];
    const float* bih = (const float*)d_in[6];
    const float* bhh = (const float*)d_in[7];
    const float* gamma = (const float*)d_in[8];
    const float* beta = (const float*)d_in[9];
    const float* fc1w = (const float*)d_in[10];
    const float* fc1b = (const float*)d_in[11];
    const float* fc2w = (const float*)d_in[12];
    const float* fc2b = (const float*)d_in[13];
    const float* fc3w = (const float*)d_in[14];
    const float* fc3b = (const float*)d_in[15];

    int N = in_sizes[0] / 32;
    int E = in_sizes[1] / 2;
    int Gn = out_size;  // 4096
    const int* srcp = ei;
    const int* dstp = ei + E;

    char* p = (char*)d_ws;
    auto alloc = [&](size_t bytes) -> char* {
        char* r = p;
        p += (bytes + 255) & ~(size_t)255;
        return r;
    };
    f16* hA = (f16*)alloc((size_t)N * H96 * 2);
    f16* hB = (f16*)alloc((size_t)N * H96 * 2);
    f16* aggf = (f16*)alloc((size_t)N * H96 * 2);
    f16* wf16 = (f16*)alloc((size_t)184320 * 2);
    f16* wpt = (f16*)alloc((size_t)LAYERS * 27648 * 2);
    int nb = (N + SCAN_B - 1) / SCAN_B;
    int* deg = (int*)alloc((size_t)N * 4);
    int* incl = (int*)alloc((size_t)nb * SCAN_B * 4);
    int* bsum = (int*)alloc((size_t)nb * 4);
    int* rs = (int*)alloc((size_t)(N + 1) * 4);
    int* cur = (int*)alloc((size_t)N * 4);
    int* es = (int*)alloc((size_t)E * 4);
    int nb2 = (Gn + SCAN_B - 1) / SCAN_B;
    int* gdeg = (int*)alloc((size_t)Gn * 4);
    int* gincl = (int*)alloc((size_t)nb2 * SCAN_B * 4);
    int* gbsum = (int*)alloc((size_t)nb2 * 4);
    int* grs = (int*)alloc((size_t)(Gn + 1) * 4);
    f16* pooled = (f16*)alloc((size_t)Gn * H96 * 2);
    f16* h1 = (f16*)alloc((size_t)Gn * 384 * 2);
    f16* h2 = (f16*)alloc((size_t)Gn * H96 * 2);

    f16* convw16 = wf16;
    f16* wih16 = wf16 + 55296;
    f16* whh16 = wf16 + 82944;
    f16* fc1w16 = wf16 + 110592;
    f16* fc2w16 = wf16 + 147456;

    hipMemsetAsync(deg, 0, (size_t)N * 4, stream);
    hipMemsetAsync(gdeg, 0, (size_t)Gn * 4, stream);

    k_f2h<<<720, 256, 0, stream>>>(conv_w, wih, whh, fc1w, fc2w, wf16);
    k_wpt<<<dim3(5, 6), 256, 0, stream>>>(wih16, convw16, wpt);
    k_pad<<<(N * H96 + 255) / 256, 256, 0, stream>>>(x, hA, N);
    // edge CSR (by dst)
    k_hist<<<(E + 255) / 256, 256, 0, stream>>>(dstp, deg, E);
    k_scan1<<<nb, SCAN_B, 0, stream>>>(deg, incl, bsum, N);
    k_scan2<<<1, 64, 0, stream>>>(bsum, nb);
    k_scan3<<<(N + 255) / 256, 256, 0, stream>>>(deg, incl, bsum, rs, cur, N, E);
    k_fill<<<(E + 255) / 256, 256, 0, stream>>>(srcp, dstp, cur, es, E);
    // graph CSR (batch sorted)
    k_hist<<<(N + 255) / 256, 256, 0, stream>>>(batch, gdeg, N);
    k_scan1<<<nb2, SCAN_B, 0, stream>>>(gdeg, gincl, gbsum, Gn);
    k_scan2<<<1, 64, 0, stream>>>(gbsum, nb2);
    k_scan3<<<(Gn + 255) / 256, 256, 0, stream>>>(gdeg, gincl, gbsum, grs, (int*)nullptr, Gn, N);

    for (int l = 0; l < LAYERS; l++) {
        f16* hin = (l & 1) ? hB : hA;
        f16* hout = (l & 1) ? hA : hB;
        k_gather<<<1280, 256, 0, stream>>>(hin, rs, es, aggf, N);
        k_gru<<<1280, 384, 0, stream>>>(aggf, hin, hout, wpt + (size_t)l * 27648, whh16, bih, bhh, N);
    }

    k_pool2<<<Gn, 128, 0, stream>>>(hA, grs, gamma, beta, pooled, Gn);
    k_mlp<3, 6, 384, true><<<dim3((Gn + 63) / 64, 4), 256, 0, stream>>>(pooled, fc1w16, fc1b, h1, Gn);
    k_mlp<12, 6, 96, true><<<dim3((Gn + 63) / 64, 1), 256, 0, stream>>>(h1, fc2w16, fc2b, h2, Gn);
    k_mlp3<<<(Gn + 255) / 256, 256, 0, stream>>>(h2, fc3w, fc3b, (float*)d_out, Gn);
}

// Round 8
// 555.544 us; speedup vs baseline: 1.0721x; 1.0329x over previous
//
#include <hip/hip_runtime.h>

#define H96 96
#define LAYERS 6
#define BN_EPS 1e-5f
#define SCAN_B 1024

typedef unsigned short u16;
typedef unsigned int u32;
typedef _Float16 f16;
typedef _Float16 h8 __attribute__((ext_vector_type(8)));
typedef float f32x4 __attribute__((ext_vector_type(4)));
typedef u32 u32x3 __attribute__((ext_vector_type(3)));

__device__ __forceinline__ float sigm(float x) { return 1.f / (1.f + __expf(-x)); }
__device__ __forceinline__ float tanh_(float x) { return 2.f / (1.f + __expf(-2.f * x)) - 1.f; }
__device__ __forceinline__ f32x4 splat4(float x) { f32x4 v = {x, x, x, x}; return v; }

struct h2s { f16 x, y; };

// unpack one dword (two f16) into two floats, by value
__device__ __forceinline__ void upk(u32 v, float& lo, float& hi) {
    union { u32 u; h2s h; } c;
    c.u = v;
    lo = (float)c.h.x;
    hi = (float)c.h.y;
}

// ---------- weight f32 -> f16 conversion ----------
__global__ void k_f2h(const float* __restrict__ convw, const float* __restrict__ wih,
                      const float* __restrict__ whh, const float* __restrict__ fc1w,
                      const float* __restrict__ fc2w, f16* __restrict__ dst) {
    int i = blockIdx.x * 256 + threadIdx.x;
    if (i >= 184320) return;
    float v;
    if (i < 55296) v = convw[i];
    else if (i < 82944) v = wih[i - 55296];
    else if (i < 110592) v = whh[i - 82944];
    else if (i < 147456) v = fc1w[i - 110592];
    else v = fc2w[i - 147456];
    dst[i] = (f16)v;
}

// ---------- WpT[l][j][k] = sum_m w_ih[j][m] * conv_w[l][k][m]  (j<288, k<96) ----------
__global__ __launch_bounds__(256) void k_wpt(const f16* __restrict__ wih16, const f16* __restrict__ convw16,
                                             f16* __restrict__ wpt) {
    int l = blockIdx.y;
    int lane = threadIdx.x & 63, wave = threadIdx.x >> 6;
    int l15 = lane & 15, q = lane >> 4;
    int rowa = blockIdx.x * 64 + wave * 16 + l15;
    if (rowa >= 288) rowa = 287;
    const f16* B = convw16 + (size_t)l * 9216;
    h8 af[3];
#pragma unroll
    for (int s = 0; s < 3; s++) af[s] = *(const h8*)(wih16 + (size_t)rowa * 96 + s * 32 + q * 8);
    f32x4 acc[6];
#pragma unroll
    for (int t = 0; t < 6; t++) acc[t] = splat4(0.f);
#pragma unroll
    for (int s = 0; s < 3; s++)
#pragma unroll
        for (int t = 0; t < 6; t++) {
            h8 b = *(const h8*)(B + (size_t)(t * 16 + l15) * 96 + s * 32 + q * 8);
            acc[t] = __builtin_amdgcn_mfma_f32_16x16x32_f16(af[s], b, acc[t], 0, 0, 0);
        }
    int rbase = blockIdx.x * 64 + wave * 16 + q * 4;
#pragma unroll
    for (int t = 0; t < 6; t++)
#pragma unroll
        for (int rr = 0; rr < 4; rr++) {
            int row = rbase + rr;
            if (row < 288) wpt[(size_t)l * 27648 + (size_t)row * 96 + t * 16 + l15] = (f16)acc[t][rr];
        }
}

// ---------- pad ----------
__global__ void k_pad(const float* __restrict__ x, f16* __restrict__ hf, int N) {
    int i = blockIdx.x * 256 + threadIdx.x;
    if (i >= N * H96) return;
    int n = i / H96, c = i - n * H96;
    float v = (c < 32) ? x[n * 32 + c] : 0.f;
    hf[i] = (f16)v;
}

// ---------- CSR build ----------
__global__ void k_hist(const int* __restrict__ key, int* __restrict__ deg, int E) {
    int e = blockIdx.x * 256 + threadIdx.x;
    if (e < E) atomicAdd(&deg[key[e]], 1);
}

__global__ __launch_bounds__(SCAN_B) void k_scan1(const int* __restrict__ deg, int* __restrict__ incl,
                                                  int* __restrict__ bsum, int N) {
    __shared__ int sh[SCAN_B];
    int i = blockIdx.x * SCAN_B + threadIdx.x;
    int v = (i < N) ? deg[i] : 0;
    sh[threadIdx.x] = v;
    __syncthreads();
    for (int off = 1; off < SCAN_B; off <<= 1) {
        int t = (threadIdx.x >= (u32)off) ? sh[threadIdx.x - off] : 0;
        __syncthreads();
        sh[threadIdx.x] += t;
        __syncthreads();
    }
    incl[blockIdx.x * SCAN_B + threadIdx.x] = sh[threadIdx.x];
    if (threadIdx.x == SCAN_B - 1) bsum[blockIdx.x] = sh[threadIdx.x];
}

__global__ void k_scan2(int* __restrict__ bsum, int nb) {
    if (blockIdx.x == 0 && threadIdx.x == 0) {
        int run = 0;
        for (int i = 0; i < nb; i++) { run += bsum[i]; bsum[i] = run; }
    }
}

__global__ void k_scan3(const int* __restrict__ deg, const int* __restrict__ incl, const int* __restrict__ bsum,
                        int* __restrict__ rs, int* __restrict__ cur, int N, int E) {
    int i = blockIdx.x * 256 + threadIdx.x;
    if (i == 0) rs[N] = E;
    if (i < N) {
        int b = i / SCAN_B;
        int off = (b > 0) ? bsum[b - 1] : 0;
        int ex = incl[i] - deg[i] + off;
        rs[i] = ex;
        if (cur) cur[i] = ex;
    }
}

__global__ void k_fill(const int* __restrict__ src, const int* __restrict__ dst, int* __restrict__ cur,
                       int* __restrict__ es, int E) {
    int e = blockIdx.x * 256 + threadIdx.x;
    if (e < E) {
        int p = atomicAdd(&cur[dst[e]], 1);
        es[p] = src[e];
    }
}

// ---------- gather: agg[n] = sum_{e in in(n)} h[src_e] ----------
// 16 nodes/block; 16-lane group per node, lane covers 6 cols (one dwordx3 per edge).
// 8-wide predicated unroll (neutral vs 4-wide; kept).
__global__ __launch_bounds__(256) void k_gather(const f16* __restrict__ hin, const int* __restrict__ rs,
                                                const int* __restrict__ es, f16* __restrict__ agg, int N) {
    int grp = threadIdx.x >> 4;
    int lane6 = threadIdx.x & 15;
    int node = blockIdx.x * 16 + grp;
    if (node >= N) return;
    int s = rs[node], e = rs[node + 1];
    float a0 = 0, a1 = 0, a2 = 0, a3 = 0, a4 = 0, a5 = 0;
    const char* basep = (const char*)hin;
    int off = lane6 * 12;
    for (int i = s; i < e; i += 8) {
        int idx[8];
        float msk[8];
        idx[0] = i; msk[0] = 1.f;
#pragma unroll
        for (int k = 1; k < 8; k++) {
            int t = i + k;
            bool v = t < e;
            idx[k] = v ? t : i;
            msk[k] = v ? 1.f : 0.f;
        }
        u32x3 vv[8];
#pragma unroll
        for (int k = 0; k < 8; k++) {
            int sn = es[idx[k]];
            vv[k] = *(const u32x3*)(basep + (size_t)sn * 192 + off);
        }
#pragma unroll
        for (int k = 0; k < 8; k++) {
            float t0, t1;
            upk(vv[k].x, t0, t1); a0 += t0 * msk[k]; a1 += t1 * msk[k];
            upk(vv[k].y, t0, t1); a2 += t0 * msk[k]; a3 += t1 * msk[k];
            upk(vv[k].z, t0, t1); a4 += t0 * msk[k]; a5 += t1 * msk[k];
        }
    }
    f16* dp = agg + (size_t)node * H96 + lane6 * 6;
    h2s p0, p1, p2;
    p0.x = (f16)a0; p0.y = (f16)a1;
    p1.x = (f16)a2; p1.y = (f16)a3;
    p2.x = (f16)a4; p2.y = (f16)a5;
    *(h2s*)(dp + 0) = p0;
    *(h2s*)(dp + 2) = p1;
    *(h2s*)(dp + 4) = p2;
}

// ---------- GRU: r7 structure + VGPR budget 128 so hoisted weights actually persist ----------
// 6 waves/block, wave w owns output cols [16w,16w+16); grid-stride over 16-row tiles.
// __launch_bounds__(384,4): 4 waves/EU min -> <=128 VGPR -> 72 weight regs stay resident.
// NOTE (rounds 0-7): this kernel is invariant to occupancy, weight residency, LDS staging,
// prefetch depth, in-wave ILP, block size, and load hoisting; its 240 TF-effective matches
// the measured GEMM ladder for 11 GFLOP. Structural latency plateau — do not micro-optimize.
__global__ __launch_bounds__(384, 4) void k_gru(const f16* __restrict__ agg, const f16* __restrict__ hin,
                                                f16* __restrict__ hout, const f16* __restrict__ wpt,
                                                const f16* __restrict__ whh, const float* __restrict__ bih,
                                                const float* __restrict__ bhh, int N) {
    int w = threadIdx.x >> 6;
    int lane = threadIdx.x & 63;
    int l15 = lane & 15, q = lane >> 4;
    int jr = w * 16 + l15;
    float b_r = bih[jr] + bhh[jr];
    float b_z = bih[96 + jr] + bhh[96 + jr];
    float b_in = bih[192 + jr];
    float b_hn = bhh[192 + jr];
    h8 wr0[3], wr1[3], wz0[3], wz1[3], wn0[3], wn1[3];
#pragma unroll
    for (int s = 0; s < 3; s++) {
        int ko = s * 32 + q * 8;
        wr0[s] = *(const h8*)(wpt + (size_t)jr * H96 + ko);
        wz0[s] = *(const h8*)(wpt + (size_t)(96 + jr) * H96 + ko);
        wn0[s] = *(const h8*)(wpt + (size_t)(192 + jr) * H96 + ko);
        wr1[s] = *(const h8*)(whh + (size_t)jr * H96 + ko);
        wz1[s] = *(const h8*)(whh + (size_t)(96 + jr) * H96 + ko);
        wn1[s] = *(const h8*)(whh + (size_t)(192 + jr) * H96 + ko);
    }
    int ntiles = (N + 15) >> 4;
    for (int tile = blockIdx.x; tile < ntiles; tile += gridDim.x) {
        int base = tile << 4;
        int rowa = base + l15;
        if (rowa >= N) rowa = N - 1;
        h8 as_[3], ah[3];
#pragma unroll
        for (int s = 0; s < 3; s++) {
            as_[s] = *(const h8*)(agg + (size_t)rowa * H96 + s * 32 + q * 8);
            ah[s] = *(const h8*)(hin + (size_t)rowa * H96 + s * 32 + q * 8);
        }
        f32x4 r = splat4(b_r), z = splat4(b_z), nn = splat4(b_in), hn = splat4(b_hn);
#pragma unroll
        for (int s = 0; s < 3; s++) {
            r = __builtin_amdgcn_mfma_f32_16x16x32_f16(as_[s], wr0[s], r, 0, 0, 0);
            r = __builtin_amdgcn_mfma_f32_16x16x32_f16(ah[s], wr1[s], r, 0, 0, 0);
            z = __builtin_amdgcn_mfma_f32_16x16x32_f16(as_[s], wz0[s], z, 0, 0, 0);
            z = __builtin_amdgcn_mfma_f32_16x16x32_f16(ah[s], wz1[s], z, 0, 0, 0);
            nn = __builtin_amdgcn_mfma_f32_16x16x32_f16(as_[s], wn0[s], nn, 0, 0, 0);
            hn = __builtin_amdgcn_mfma_f32_16x16x32_f16(ah[s], wn1[s], hn, 0, 0, 0);
        }
        int rbase = base + q * 4;
#pragma unroll
        for (int rr = 0; rr < 4; rr++) {
            int row = rbase + rr;
            if (row < N) {
                float rv = sigm(r[rr]);
                float zv = sigm(z[rr]);
                float nv = tanh_(nn[rr] + rv * hn[rr]);
                size_t idx = (size_t)row * H96 + w * 16 + l15;
                float hold = (float)hin[idx];
                float hnew = (1.f - zv) * nv + zv * hold;
                hout[idx] = (f16)hnew;
            }
        }
    }
}

// ---------- fused pool + BN ----------
__global__ void k_pool2(const f16* __restrict__ hf, const int* __restrict__ grs,
                        const float* __restrict__ gamma, const float* __restrict__ beta,
                        f16* __restrict__ pooled, int Gn) {
    int g = blockIdx.x;
    int c = threadIdx.x;
    if (g >= Gn || c >= H96) return;
    int s = grs[g], e = grs[g + 1];
    float sum = 0.f;
    for (int n = s; n < e; n++) sum += fmaxf((float)hf[(size_t)n * H96 + c], 0.f);
    float cnt = fmaxf((float)(e - s), 1.f);
    float val = (sum / cnt) * (gamma[c] * rsqrtf(1.f + BN_EPS)) + beta[c];
    pooled[(size_t)g * H96 + c] = (f16)val;
}

// ---------- MLP GEMM: out = act(A @ W^T + b); blockIdx.y selects a column group ----------
template <int KS, int NT, int OUTW, bool RELU>
__global__ __launch_bounds__(256) void k_mlp(const f16* __restrict__ A, const f16* __restrict__ W,
                                             const float* __restrict__ bias, f16* __restrict__ out, int M) {
    int lane = threadIdx.x & 63, wave = threadIdx.x >> 6;
    int l15 = lane & 15, q = lane >> 4;
    int colBase = blockIdx.y * (NT * 16);
    int tile = blockIdx.x;
    int rowa = tile * 64 + wave * 16 + l15;
    if (rowa >= M) rowa = M - 1;
    h8 af[KS];
#pragma unroll
    for (int s = 0; s < KS; s++) af[s] = *(const h8*)(A + (size_t)rowa * (KS * 32) + s * 32 + q * 8);
    f32x4 acc[NT];
#pragma unroll
    for (int t = 0; t < NT; t++) acc[t] = splat4(0.f);
#pragma unroll
    for (int s = 0; s < KS; s++)
#pragma unroll
        for (int t = 0; t < NT; t++) {
            h8 b = *(const h8*)(W + (size_t)(colBase + t * 16 + l15) * (KS * 32) + s * 32 + q * 8);
            acc[t] = __builtin_amdgcn_mfma_f32_16x16x32_f16(af[s], b, acc[t], 0, 0, 0);
        }
    int rbase = tile * 64 + wave * 16 + q * 4;
#pragma unroll
    for (int t = 0; t < NT; t++) {
        float bv = bias[colBase + t * 16 + l15];
#pragma unroll
        for (int rr = 0; rr < 4; rr++) {
            int row = rbase + rr;
            if (row >= M) continue;
            float v = acc[t][rr] + bv;
            if (RELU) v = fmaxf(v, 0.f);
            out[(size_t)row * OUTW + colBase + t * 16 + l15] = (f16)v;
        }
    }
}

__global__ void k_mlp3(const f16* __restrict__ h2, const float* __restrict__ w, const float* __restrict__ b,
                       float* __restrict__ out, int M) {
    int g = blockIdx.x * 256 + threadIdx.x;
    if (g >= M) return;
    float acc = 0.f;
    for (int k = 0; k < H96; k++) acc += (float)h2[(size_t)g * H96 + k] * w[k];
    out[g] = acc + b[0];
}

extern "C" void kernel_launch(void* const* d_in, const int* in_sizes, int n_in, void* d_out, int out_size,
                              void* d_ws, size_t ws_size, hipStream_t stream) {
    const float* x = (const float*)d_in[0];
    const int* ei = (const int*)d_in[1];
    const int* batch = (const int*)d_in[2];
    const float* conv_w = (const float*)d_in[3];
    const float* wih = (const float*)d_in[4];
    const float* whh = (const float*)d_in[5];
    const float* bih = (const float*)d_in[6];
    const float* bhh = (const float*)d_in[7];
    const float* gamma = (const float*)d_in[8];
    const float* beta = (const float*)d_in[9];
    const float* fc1w = (const float*)d_in[10];
    const float* fc1b = (const float*)d_in[11];
    const float* fc2w = (const float*)d_in[12];
    const float* fc2b = (const float*)d_in[13];
    const float* fc3w = (const float*)d_in[14];
    const float* fc3b = (const float*)d_in[15];

    int N = in_sizes[0] / 32;
    int E = in_sizes[1] / 2;
    int Gn = out_size;  // 4096
    const int* srcp = ei;
    const int* dstp = ei + E;

    char* p = (char*)d_ws;
    auto alloc = [&](size_t bytes) -> char* {
        char* r = p;
        p += (bytes + 255) & ~(size_t)255;
        return r;
    };
    f16* hA = (f16*)alloc((size_t)N * H96 * 2);
    f16* hB = (f16*)alloc((size_t)N * H96 * 2);
    f16* aggf = (f16*)alloc((size_t)N * H96 * 2);
    f16* wf16 = (f16*)alloc((size_t)184320 * 2);
    f16* wpt = (f16*)alloc((size_t)LAYERS * 27648 * 2);
    int nb = (N + SCAN_B - 1) / SCAN_B;
    int* deg = (int*)alloc((size_t)N * 4);
    int* incl = (int*)alloc((size_t)nb * SCAN_B * 4);
    int* bsum = (int*)alloc((size_t)nb * 4);
    int* rs = (int*)alloc((size_t)(N + 1) * 4);
    int* cur = (int*)alloc((size_t)N * 4);
    int* es = (int*)alloc((size_t)E * 4);
    int nb2 = (Gn + SCAN_B - 1) / SCAN_B;
    int* gdeg = (int*)alloc((size_t)Gn * 4);
    int* gincl = (int*)alloc((size_t)nb2 * SCAN_B * 4);
    int* gbsum = (int*)alloc((size_t)nb2 * 4);
    int* grs = (int*)alloc((size_t)(Gn + 1) * 4);
    f16* pooled = (f16*)alloc((size_t)Gn * H96 * 2);
    f16* h1 = (f16*)alloc((size_t)Gn * 384 * 2);
    f16* h2 = (f16*)alloc((size_t)Gn * H96 * 2);

    f16* convw16 = wf16;
    f16* wih16 = wf16 + 55296;
    f16* whh16 = wf16 + 82944;
    f16* fc1w16 = wf16 + 110592;
    f16* fc2w16 = wf16 + 147456;

    hipMemsetAsync(deg, 0, (size_t)N * 4, stream);
    hipMemsetAsync(gdeg, 0, (size_t)Gn * 4, stream);

    k_f2h<<<720, 256, 0, stream>>>(conv_w, wih, whh, fc1w, fc2w, wf16);
    k_wpt<<<dim3(5, 6), 256, 0, stream>>>(wih16, convw16, wpt);
    k_pad<<<(N * H96 + 255) / 256, 256, 0, stream>>>(x, hA, N);
    // edge CSR (by dst)
    k_hist<<<(E + 255) / 256, 256, 0, stream>>>(dstp, deg, E);
    k_scan1<<<nb, SCAN_B, 0, stream>>>(deg, incl, bsum, N);
    k_scan2<<<1, 64, 0, stream>>>(bsum, nb);
    k_scan3<<<(N + 255) / 256, 256, 0, stream>>>(deg, incl, bsum, rs, cur, N, E);
    k_fill<<<(E + 255) / 256, 256, 0, stream>>>(srcp, dstp, cur, es, E);
    // graph CSR (batch sorted)
    k_hist<<<(N + 255) / 256, 256, 0, stream>>>(batch, gdeg, N);
    k_scan1<<<nb2, SCAN_B, 0, stream>>>(gdeg, gincl, gbsum, Gn);
    k_scan2<<<1, 64, 0, stream>>>(gbsum, nb2);
    k_scan3<<<(Gn + 255) / 256, 256, 0, stream>>>(gdeg, gincl, gbsum, grs, (int*)nullptr, Gn, N);

    int nt16 = (N + 15) / 16;
    for (int l = 0; l < LAYERS; l++) {
        f16* hin = (l & 1) ? hB : hA;
        f16* hout = (l & 1) ? hA : hB;
        k_gather<<<nt16, 256, 0, stream>>>(hin, rs, es, aggf, N);
        k_gru<<<1280, 384, 0, stream>>>(aggf, hin, hout, wpt + (size_t)l * 27648, whh16, bih, bhh, N);
    }

    k_pool2<<<Gn, 128, 0, stream>>>(hA, grs, gamma, beta, pooled, Gn);
    k_mlp<3, 6, 384, true><<<dim3((Gn + 63) / 64, 4), 256, 0, stream>>>(pooled, fc1w16, fc1b, h1, Gn);
    k_mlp<12, 6, 96, true><<<dim3((Gn + 63) / 64, 1), 256, 0, stream>>>(h1, fc2w16, fc2b, h2, Gn);
    k_mlp3<<<(Gn + 255) / 256, 256, 0, stream>>>(h2, fc3w, fc3b, (float*)d_out, Gn);
}